// Round 1
// baseline (356.314 us; speedup 1.0000x reference)
//
#include <hip/hip_runtime.h>
#include <stdint.h>

#define BATCH 256
#define CIN   64
#define LIN   4096
#define PADN  3
#define LPAD  (LIN + 2*PADN)   /* 4102 */
#define COUT  128
#define KW    7
#define LPOOL 2048
#define NPERCH (256LL * 2048LL) /* per-channel element count for BN stats */

typedef unsigned long long u64;

// ---------------------------------------------------------------------------
// pack_x: (B, 64, 4096) fp32 -> per (b, padded position) 64-bit sign word +
// 64-bit nonzero word (bit c = channel c). Padding value -1 => sign=0, z=1.
// ---------------------------------------------------------------------------
__global__ __launch_bounds__(256) void pack_x_kernel(const float* __restrict__ x,
                                                     ulonglong2* __restrict__ px)
{
    int pos = blockIdx.x * 256 + threadIdx.x;
    int b   = blockIdx.y;
    if (pos >= LPAD) return;
    u64 s = 0, z = 0;
    int lx = pos - PADN;
    if (lx < 0 || lx >= LIN) {
        s = 0;        // -1 is not > 0
        z = ~0ull;    // -1 != 0
    } else {
        const float* xb = x + (size_t)b * CIN * LIN + lx;
        #pragma unroll
        for (int c = 0; c < CIN; ++c) {
            float v = xb[(size_t)c * LIN];
            s |= ((u64)(v > 0.0f))  << c;
            z |= ((u64)(v != 0.0f)) << c;
        }
    }
    px[(size_t)b * LPAD + pos] = make_ulonglong2(s, z);
}

// ---------------------------------------------------------------------------
// pack_w: (128, 64, 7) fp32 -> per (co, k) sign/nonzero words. Sets wflag if
// any W element is exactly zero (forces exact slow path everywhere).
// ---------------------------------------------------------------------------
__global__ void pack_w_kernel(const float* __restrict__ w,
                              ulonglong2* __restrict__ pw,
                              unsigned int* __restrict__ wflag)
{
    int t = blockIdx.x * blockDim.x + threadIdx.x;
    if (t >= COUT * KW) return;
    int co = t / KW, k = t % KW;
    u64 s = 0, z = 0;
    for (int c = 0; c < CIN; ++c) {
        float v = w[((size_t)co * CIN + c) * KW + k];
        s |= ((u64)(v > 0.0f))  << c;
        z |= ((u64)(v != 0.0f)) << c;
    }
    pw[t] = make_ulonglong2(s, z);
    if (z != ~0ull) atomicOr(wflag, 1u);
}

// ---------------------------------------------------------------------------
// Shared conv core: compute pooled pre-PReLU integer p for (b, co, lp).
// Thread holds 8 word-pairs (positions 2lp..2lp+7) in registers.
// ---------------------------------------------------------------------------
__device__ __forceinline__ int conv_pooled(const ulonglong2 w8[8],
                                           const ulonglong2* __restrict__ wj,
                                           bool fast)
{
    if (fast) {
        int c0 = 0, c1 = 0;
        #pragma unroll
        for (int k = 0; k < KW; ++k) {
            u64 wsk = wj[k].x;
            c0 += __popcll(w8[k].x     ^ wsk);
            c1 += __popcll(w8[k + 1].x ^ wsk);
        }
        int m = (c0 < c1) ? c0 : c1;
        return (CIN * KW) - 2 * m;
    } else {
        int d0 = 0, d1 = 0;
        #pragma unroll
        for (int k = 0; k < KW; ++k) {
            u64 wsk = wj[k].x, wzk = wj[k].y;
            u64 m0 = w8[k].y     & wzk;
            u64 m1 = w8[k + 1].y & wzk;
            d0 += __popcll(m0) - 2 * __popcll((w8[k].x     ^ wsk) & m0);
            d1 += __popcll(m1) - 2 * __popcll((w8[k + 1].x ^ wsk) & m1);
        }
        return (d0 > d1) ? d0 : d1;
    }
}

// ---------------------------------------------------------------------------
// Pass A: conv + pool + PReLU-split integer stats per channel.
// Block = (co group of 4, b). 256 threads x 8 iters cover lp in [0,2048).
// ---------------------------------------------------------------------------
__global__ __launch_bounds__(256) void conv_stats_kernel(
    const ulonglong2* __restrict__ px, const ulonglong2* __restrict__ pw,
    const unsigned int* __restrict__ wflag, unsigned long long* __restrict__ stats)
{
    const int tid = threadIdx.x;
    const int co0 = blockIdx.x * 4;
    const int b   = blockIdx.y;
    const bool wbad = (*wflag != 0);

    int sp[4] = {0,0,0,0}, sn[4] = {0,0,0,0}, qp[4] = {0,0,0,0}, qn[4] = {0,0,0,0};

    for (int i = 0; i < 8; ++i) {
        int lp = i * 256 + tid;
        const ulonglong2* xw = px + (size_t)b * LPAD + 2 * lp;
        ulonglong2 w8[8];
        #pragma unroll
        for (int t = 0; t < 8; ++t) w8[t] = xw[t];
        u64 zand = w8[0].y & w8[1].y & w8[2].y & w8[3].y &
                   w8[4].y & w8[5].y & w8[6].y & w8[7].y;
        bool fast = (zand == ~0ull) && !wbad;
        #pragma unroll
        for (int j = 0; j < 4; ++j) {
            int p = conv_pooled(w8, pw + (size_t)(co0 + j) * KW, fast);
            if (p > 0) { sp[j] += p; qp[j] += p * p; }
            else       { sn[j] += p; qn[j] += p * p; }
        }
    }

    // block reduction of 16 int32 values
    int vals[16];
    #pragma unroll
    for (int j = 0; j < 4; ++j) {
        vals[j*4+0] = sp[j]; vals[j*4+1] = sn[j];
        vals[j*4+2] = qp[j]; vals[j*4+3] = qn[j];
    }
    #pragma unroll
    for (int v = 0; v < 16; ++v)
        for (int off = 32; off >= 1; off >>= 1)
            vals[v] += __shfl_down(vals[v], off, 64);

    __shared__ int redu[4][16];
    int wid = tid >> 6, lane = tid & 63;
    if (lane == 0) {
        #pragma unroll
        for (int v = 0; v < 16; ++v) redu[wid][v] = vals[v];
    }
    __syncthreads();
    if (tid < 16) {
        int s = redu[0][tid] + redu[1][tid] + redu[2][tid] + redu[3][tid];
        int j = tid >> 2, si = tid & 3;
        atomicAdd(&stats[(size_t)(co0 + j) * 4 + si],
                  (unsigned long long)(long long)s);
    }
}

// ---------------------------------------------------------------------------
// finalize: per-channel BN scale/shift from exact integer sums (double math).
// y = p>0 ? p : a*p ; sum_y = sp + a*sn ; sumsq_y = qp + a^2*qn.
// ---------------------------------------------------------------------------
__global__ void finalize_kernel(const unsigned long long* __restrict__ stats,
                                const float* __restrict__ alpha,
                                const float* __restrict__ gamma,
                                const float* __restrict__ beta,
                                float2* __restrict__ scsh)
{
    int c = threadIdx.x;
    if (c >= COUT) return;
    long long sp = (long long)stats[c*4+0];
    long long sn = (long long)stats[c*4+1];
    long long qp = (long long)stats[c*4+2];
    long long qn = (long long)stats[c*4+3];
    double a   = (double)alpha[0];
    double N   = (double)NPERCH;
    double sum = (double)sp + a * (double)sn;
    double ssq = (double)qp + a * a * (double)qn;
    double mean = sum / N;
    double var  = ssq / N - mean * mean;
    double inv  = 1.0 / sqrt(var + 1e-5);
    double g    = (double)gamma[c];
    float sc = (float)(g * inv);
    float sh = (float)((double)beta[c] - mean * g * inv);
    scsh[c] = make_float2(sc, sh);
}

// ---------------------------------------------------------------------------
// Pass B: conv + pool + PReLU + BN affine, write fp32 output.
// ---------------------------------------------------------------------------
__global__ __launch_bounds__(256) void conv_write_kernel(
    const ulonglong2* __restrict__ px, const ulonglong2* __restrict__ pw,
    const unsigned int* __restrict__ wflag, const float2* __restrict__ scsh,
    const float* __restrict__ alpha, float* __restrict__ out)
{
    const int tid = threadIdx.x;
    const int co0 = blockIdx.x * 4;
    const int b   = blockIdx.y;
    const bool wbad = (*wflag != 0);
    const float a = alpha[0];
    float2 ss[4];
    #pragma unroll
    for (int j = 0; j < 4; ++j) ss[j] = scsh[co0 + j];

    for (int i = 0; i < 8; ++i) {
        int lp = i * 256 + tid;
        const ulonglong2* xw = px + (size_t)b * LPAD + 2 * lp;
        ulonglong2 w8[8];
        #pragma unroll
        for (int t = 0; t < 8; ++t) w8[t] = xw[t];
        u64 zand = w8[0].y & w8[1].y & w8[2].y & w8[3].y &
                   w8[4].y & w8[5].y & w8[6].y & w8[7].y;
        bool fast = (zand == ~0ull) && !wbad;
        #pragma unroll
        for (int j = 0; j < 4; ++j) {
            int p = conv_pooled(w8, pw + (size_t)(co0 + j) * KW, fast);
            float yf = (p > 0) ? (float)p : a * (float)p;
            out[((size_t)b * COUT + co0 + j) * LPOOL + lp] = fmaf(yf, ss[j].x, ss[j].y);
        }
    }
}

// ---------------------------------------------------------------------------
extern "C" void kernel_launch(void* const* d_in, const int* in_sizes, int n_in,
                              void* d_out, int out_size, void* d_ws, size_t ws_size,
                              hipStream_t stream)
{
    const float* x     = (const float*)d_in[0];
    const float* W     = (const float*)d_in[1];
    const float* alpha = (const float*)d_in[2];
    const float* gamma = (const float*)d_in[3];
    const float* beta  = (const float*)d_in[4];
    float* out = (float*)d_out;

    char* ws = (char*)d_ws;
    size_t off = 0;
    ulonglong2* px = (ulonglong2*)(ws + off); off += (size_t)BATCH * LPAD * sizeof(ulonglong2);
    ulonglong2* pw = (ulonglong2*)(ws + off); off += (size_t)COUT * KW * sizeof(ulonglong2);
    unsigned long long* stats = (unsigned long long*)(ws + off); off += (size_t)COUT * 4 * 8;
    unsigned int* wflag = (unsigned int*)(ws + off); off += 16;
    float2* scsh = (float2*)(ws + off); off += (size_t)COUT * 8;

    // zero stats + wflag (harness poisons ws; no re-poison between replays)
    hipMemsetAsync(stats, 0, (size_t)COUT * 4 * 8 + 16, stream);

    pack_x_kernel<<<dim3((LPAD + 255) / 256, BATCH), 256, 0, stream>>>(x, px);
    pack_w_kernel<<<dim3(4), 256, 0, stream>>>(W, pw, wflag);
    conv_stats_kernel<<<dim3(COUT / 4, BATCH), 256, 0, stream>>>(px, pw, wflag, stats);
    finalize_kernel<<<dim3(1), 128, 0, stream>>>(stats, alpha, gamma, beta, scsh);
    conv_write_kernel<<<dim3(COUT / 4, BATCH), 256, 0, stream>>>(px, pw, wflag, scsh, alpha, out);
}